// Round 1
// baseline (102.342 us; speedup 1.0000x reference)
//
#include <hip/hip_runtime.h>

#define NB   8
#define CIN  32
#define HH   28
#define WW   28
#define OC   64
#define HWSZ (HH*WW)            // 784
#define TOTAL (NB*OC*HWSZ)      // 401408
#define CNT  (NB*HWSZ)          // 6272 elements per channel for BN stats

#define TROWS 4                 // staged input rows: h0-1 .. h0+2
#define TCOLS 32                // padded cols (-1..30); power-of-2 -> shift indexing
#define TSZ  (CIN*TROWS*TCOLS)  // 4096 floats = 16 KB LDS

#define CPW  4                  // output channels per wave (4 waves -> 16 ch/block)
#define CHGRP 4                 // channel groups of 16
// grid: n(8) x rowpair(14) x chgrp(4) = 448 blocks

__global__ __launch_bounds__(256) void adder_stats_kernel(
    const float* __restrict__ x, const float* __restrict__ Wt,
    float* __restrict__ raw, double* __restrict__ S, double* __restrict__ S2)
{
    __shared__ float xs[TSZ];
    const int t     = threadIdx.x;
    const int bid   = blockIdx.x;
    const int chgrp = bid & (CHGRP-1);
    const int rp    = (bid >> 2) % 14;
    const int n     = bid / (CHGRP * 14);
    const int h0    = rp * 2;

    // ---- stage x strip: ALL 32 channels, rows h0-1..h0+2, cols -1..30 ----
    // TSZ/256 = 16 exact iterations; all index math is shifts/masks.
    for (int i = t; i < TSZ; i += 256) {
        int cc  = i >> 7;          // /128
        int r   = (i >> 5) & 3;    // /32 % 4
        int col = i & 31;
        int hh  = h0 - 1 + r;
        int ww  = col - 1;
        float v = 0.0f;
        if (hh >= 0 && hh < HH && (unsigned)ww < (unsigned)WW)
            v = x[((n*CIN + cc)*HH + hh)*WW + ww];
        xs[i] = v;
    }
    __syncthreads();

    const int lane  = t & 63;
    const int g     = __builtin_amdgcn_readfirstlane(t >> 6); // wave id, uniform
    const bool valid = lane < 56;                 // 2 rows x 28 cols
    const int p     = valid ? lane : 0;
    const int pr    = p / WW;                     // 0 or 1
    const int pw    = p % WW;
    const int o_base = chgrp*16 + g*CPW;
    const int b0    = pr*TCOLS + pw;              // row/col base inside channel 0

    float acc[CPW];
    #pragma unroll
    for (int oo = 0; oo < CPW; ++oo) acc[oo] = 0.0f;

    // 9 LDS reads per cc amortized over 4 output channels (72 VALU / 9 reads).
    // Addresses are base + compile-time immediates -> compiler folds to
    // ds_read offsets and merges adjacent cols into ds_read2_b32.
    for (int cc = 0; cc < CIN; ++cc) {
        float xr[9];
        #pragma unroll
        for (int dr = 0; dr < 3; ++dr)
            #pragma unroll
            for (int dc = 0; dc < 3; ++dc)
                xr[dr*3+dc] = xs[(cc << 7) + b0 + (dr << 5) + dc];
        #pragma unroll
        for (int oo = 0; oo < CPW; ++oo) {
            const float* wp = Wt + ((o_base + oo)*CIN + cc)*9; // wave-uniform -> s_load
            #pragma unroll
            for (int j = 0; j < 9; ++j)
                acc[oo] += __builtin_fabsf(xr[j] - wp[j]);
        }
    }

    // ---- write full (un-split) raw sums ----
    if (valid) {
        #pragma unroll
        for (int oo = 0; oo < CPW; ++oo)
            raw[((n*OC + o_base + oo)*HH + (h0 + pr))*WW + pw] = -acc[oo];
    }

    // ---- fused BN statistics: f32 wave-reduce (56 vals) + f64 atomics ----
    #pragma unroll
    for (int oo = 0; oo < CPW; ++oo) {
        float v  = valid ? -acc[oo] : 0.0f;
        float s  = v;
        float s2 = v * v;
        #pragma unroll
        for (int off = 32; off >= 1; off >>= 1) {
            s  += __shfl_xor(s,  off, 64);
            s2 += __shfl_xor(s2, off, 64);
        }
        if (lane == 0) {
            atomicAdd(&S [o_base + oo], (double)s);
            atomicAdd(&S2[o_base + oo], (double)s2);
        }
    }
}

// y = raw*scl + sh, scale/shift finalized inline from the f64 accumulators
__global__ __launch_bounds__(256) void bn_kernel(
    const float* __restrict__ raw,
    const double* __restrict__ S, const double* __restrict__ S2,
    const float* __restrict__ gamma, const float* __restrict__ beta,
    float* __restrict__ out)
{
    int i4 = blockIdx.x * 256 + threadIdx.x;   // float4 index
    if (i4 >= TOTAL/4) return;
    int o = (i4 / (HWSZ/4)) & (OC - 1);
    double mean = S[o]  * (1.0 / CNT);
    double var  = S2[o] * (1.0 / CNT) - mean * mean;
    double inv  = 1.0 / sqrt(var + 1e-5);
    double gs   = (double)gamma[o] * inv;
    float scl   = (float)gs;
    float sh    = (float)((double)beta[o] - mean * gs);
    float4 a = ((const float4*)raw)[i4];
    float4 v;
    v.x = a.x * scl + sh;
    v.y = a.y * scl + sh;
    v.z = a.z * scl + sh;
    v.w = a.w * scl + sh;
    ((float4*)out)[i4] = v;
}

extern "C" void kernel_launch(void* const* d_in, const int* in_sizes, int n_in,
                              void* d_out, int out_size, void* d_ws, size_t ws_size,
                              hipStream_t stream) {
    const float* x     = (const float*)d_in[0];
    const float* Wt    = (const float*)d_in[1];
    const float* gamma = (const float*)d_in[2];
    const float* beta  = (const float*)d_in[3];
    float* out = (float*)d_out;

    // ws layout: [0,512)   S  (64 doubles)
    //            [512,1024) S2 (64 doubles)
    //            [4096, 4096+TOTAL*4) raw
    double* S   = (double*)d_ws;
    double* S2  = S + 64;
    float*  raw = (float*)((char*)d_ws + 4096);

    hipMemsetAsync(d_ws, 0, 1024, stream);   // zero the stat accumulators (capturable)
    adder_stats_kernel<<<NB*14*CHGRP, 256, 0, stream>>>(x, Wt, raw, S, S2);
    bn_kernel<<<(TOTAL/4 + 255) / 256, 256, 0, stream>>>(raw, S, S2, gamma, beta, out);
}

// Round 2
// 83.152 us; speedup vs baseline: 1.2308x; 1.2308x over previous
//
#include <hip/hip_runtime.h>

#define NB   8
#define CIN  32
#define HH   28
#define WW   28
#define OC   64
#define HWSZ (HH*WW)            // 784
#define TOTAL (NB*OC*HWSZ)      // 401408
#define CNT  (NB*HWSZ)          // 6272 elements per channel for BN stats

#define TROWS 4                 // staged input rows: h0-1 .. h0+2
#define TCOLS 32                // padded cols (-1..30); power-of-2 -> shift indexing
#define TSZ  (CIN*TROWS*TCOLS)  // 4096 floats = 16 KB LDS

#define CPW  2                  // output channels per wave (4 waves -> 8 ch/block)
#define CHGRP 8                 // 8 channel groups of 8
#define NCOPY 32                // scattered stat accumulator copies (32 x 128 doubles)
// grid: n(8) x rowpair(14) x chgrp(8) = 896 blocks -> 3584 waves = 3.5/SIMD

__global__ __launch_bounds__(256) void adder_stats_kernel(
    const float* __restrict__ x, const float* __restrict__ Wt,
    float* __restrict__ raw, double* __restrict__ Sbuf)
{
    __shared__ float xs[TSZ];
    const int t     = threadIdx.x;
    const int bid   = blockIdx.x;
    const int chgrp = bid & (CHGRP-1);
    const int sp    = bid >> 3;          // spatial tile index: rp + 14*n
    const int rp    = sp % 14;
    const int n     = bid / (CHGRP * 14);
    const int h0    = rp * 2;
    const int copy  = sp & (NCOPY-1);    // spreads each channel's adds over all copies

    // ---- stage x strip: ALL 32 channels, rows h0-1..h0+2, cols -1..30 ----
    for (int i = t; i < TSZ; i += 256) {
        int cc  = i >> 7;          // /128
        int r   = (i >> 5) & 3;    // /32 % 4
        int col = i & 31;
        int hh  = h0 - 1 + r;
        int ww  = col - 1;
        float v = 0.0f;
        if (hh >= 0 && hh < HH && (unsigned)ww < (unsigned)WW)
            v = x[((n*CIN + cc)*HH + hh)*WW + ww];
        xs[i] = v;
    }
    __syncthreads();

    const int lane  = t & 63;
    const int g     = __builtin_amdgcn_readfirstlane(t >> 6); // wave id, uniform
    const bool valid = lane < 56;                 // 2 rows x 28 cols
    const int p     = valid ? lane : 0;
    const int pr    = p / WW;                     // 0 or 1
    const int pw    = p % WW;
    const int o_base = chgrp*8 + g*CPW;
    const int b0    = pr*TCOLS + pw;              // base inside channel 0

    float acc[CPW];
    #pragma unroll
    for (int oo = 0; oo < CPW; ++oo) acc[oo] = 0.0f;

    // 9 LDS reads per cc feed 2*18 = 36 VALU inst; addresses are base +
    // compile-time immediates -> ds_read offsets (b96/read2 merges).
    for (int cc = 0; cc < CIN; ++cc) {
        float xr[9];
        #pragma unroll
        for (int dr = 0; dr < 3; ++dr)
            #pragma unroll
            for (int dc = 0; dc < 3; ++dc)
                xr[dr*3+dc] = xs[(cc << 7) + b0 + (dr << 5) + dc];
        #pragma unroll
        for (int oo = 0; oo < CPW; ++oo) {
            const float* wp = Wt + ((o_base + oo)*CIN + cc)*9; // wave-uniform -> s_load
            #pragma unroll
            for (int j = 0; j < 9; ++j)
                acc[oo] += __builtin_fabsf(xr[j] - wp[j]);
        }
    }

    // ---- write full raw sums ----
    if (valid) {
        #pragma unroll
        for (int oo = 0; oo < CPW; ++oo)
            raw[((n*OC + o_base + oo)*HH + (h0 + pr))*WW + pw] = -acc[oo];
    }

    // ---- fused BN stats: f32 wave-reduce, f64 atomics scattered over NCOPY ----
    #pragma unroll
    for (int oo = 0; oo < CPW; ++oo) {
        float v  = valid ? -acc[oo] : 0.0f;
        float s  = v;
        float s2 = v * v;
        #pragma unroll
        for (int off = 32; off >= 1; off >>= 1) {
            s  += __shfl_xor(s,  off, 64);
            s2 += __shfl_xor(s2, off, 64);
        }
        if (lane == 0) {
            double* Sc = Sbuf + copy*128;
            atomicAdd(&Sc[     o_base + oo], (double)s);
            atomicAdd(&Sc[64 + o_base + oo], (double)s2);
        }
    }
}

// y = raw*scl + sh; scale/shift finalized inline from the NCOPY f64 partials
__global__ __launch_bounds__(256) void bn_kernel(
    const float* __restrict__ raw, const double* __restrict__ Sbuf,
    const float* __restrict__ gamma, const float* __restrict__ beta,
    float* __restrict__ out)
{
    int i4 = blockIdx.x * 256 + threadIdx.x;   // float4 index
    if (i4 >= TOTAL/4) return;
    int o = (i4 / (HWSZ/4)) & (OC - 1);
    double S = 0.0, S2 = 0.0;
    #pragma unroll 8
    for (int k = 0; k < NCOPY; ++k) {
        S  += Sbuf[k*128 + o];
        S2 += Sbuf[k*128 + 64 + o];
    }
    double mean = S  * (1.0 / CNT);
    double var  = S2 * (1.0 / CNT) - mean * mean;
    double inv  = 1.0 / sqrt(var + 1e-5);
    double gs   = (double)gamma[o] * inv;
    float scl   = (float)gs;
    float sh    = (float)((double)beta[o] - mean * gs);
    float4 a = ((const float4*)raw)[i4];
    float4 v;
    v.x = a.x * scl + sh;
    v.y = a.y * scl + sh;
    v.z = a.z * scl + sh;
    v.w = a.w * scl + sh;
    ((float4*)out)[i4] = v;
}

extern "C" void kernel_launch(void* const* d_in, const int* in_sizes, int n_in,
                              void* d_out, int out_size, void* d_ws, size_t ws_size,
                              hipStream_t stream) {
    const float* x     = (const float*)d_in[0];
    const float* Wt    = (const float*)d_in[1];
    const float* gamma = (const float*)d_in[2];
    const float* beta  = (const float*)d_in[3];
    float* out = (float*)d_out;

    // ws layout: [0, 32768)  Sbuf: NCOPY x (64 S + 64 S2) doubles
    //            [32768, 32768+TOTAL*4) raw
    double* Sbuf = (double*)d_ws;
    float*  raw  = (float*)((char*)d_ws + NCOPY*128*sizeof(double));

    hipMemsetAsync(d_ws, 0, NCOPY*128*sizeof(double), stream);
    adder_stats_kernel<<<NB*14*CHGRP, 256, 0, stream>>>(x, Wt, raw, Sbuf);
    bn_kernel<<<(TOTAL/4 + 255) / 256, 256, 0, stream>>>(raw, Sbuf, gamma, beta, out);
}